// Round 1
// baseline (398.704 us; speedup 1.0000x reference)
//
#include <hip/hip_runtime.h>
#include <hip/hip_bf16.h>

#define B_  4
#define H_  16
#define S_  2048
#define DK_ 64
#define L2E 1.44269504f

typedef __attribute__((ext_vector_type(8))) short short8;
typedef __attribute__((ext_vector_type(4))) float f32x4;

__device__ __forceinline__ unsigned short f2bf(float f) {
    union { float f; unsigned int u; } x; x.f = f;
    unsigned int r = x.u + 0x7fffu + ((x.u >> 16) & 1u);
    return (unsigned short)(r >> 16);
}

__global__ __launch_bounds__(256) void attn_fwd(
    const float* __restrict__ q, const float* __restrict__ k,
    const float* __restrict__ v, const int* __restrict__ sen_len,
    float* __restrict__ out)
{
    const int qt  = blockIdx.x;          // q tile 0..31
    const int bh  = blockIdx.y;          // 0..63
    const int b   = bh >> 4;
    const int q0  = qt * 64;
    const long base = (long)bh * S_ * DK_;

    const int tid  = threadIdx.x;
    const int wid  = tid >> 6;           // wave 0..3
    const int lane = tid & 63;
    const int l15  = lane & 15;
    const int lg   = lane >> 4;          // 0..3

    // LDS: bf16 tiles, rows padded to 72 elems (144B) -> 2-way bank alias only
    __shared__ unsigned short Kt[64][72];     // [key][d]
    __shared__ unsigned short Vt[64][72];     // [d][key]  (transposed V)
    __shared__ unsigned short Pl[4][16][72];  // per-wave P tile [qrow][key]

    const int slen = sen_len[b];

    // ---- load Q fragments (held whole kernel) ----
    // A-frag layout: A[m][kd], m = lane&15, kd = ks*32 + lg*8 + i
    short8 qf[2];
    {
        const int row = q0 + wid * 16 + l15;
        #pragma unroll
        for (int ks = 0; ks < 2; ++ks) {
            const float4* p = (const float4*)(q + base + (long)row * DK_ + ks * 32 + lg * 8);
            float4 a = p[0], c = p[1];
            short8 f;
            f[0] = (short)f2bf(a.x); f[1] = (short)f2bf(a.y);
            f[2] = (short)f2bf(a.z); f[3] = (short)f2bf(a.w);
            f[4] = (short)f2bf(c.x); f[5] = (short)f2bf(c.y);
            f[6] = (short)f2bf(c.z); f[7] = (short)f2bf(c.w);
            qf[ks] = f;
        }
    }

    f32x4 O[4];
    #pragma unroll
    for (int dt = 0; dt < 4; ++dt) O[dt] = (f32x4){0.f, 0.f, 0.f, 0.f};
    float m_[4], l_[4];
    #pragma unroll
    for (int r = 0; r < 4; ++r) { m_[r] = -INFINITY; l_[r] = 0.f; }

    const int nk     = min(q0 + 64, slen);
    const int ntiles = (nk + 63) >> 6;
    const int rowb   = q0 + wid * 16 + lg * 4;

    for (int t = 0; t < ntiles; ++t) {
        const int k0 = t * 64;

        // ---- stage K (row-major) and V (transposed) as bf16 ----
        #pragma unroll
        for (int it = 0; it < 4; ++it) {
            const int c  = tid + 256 * it;    // 0..1023 float4-chunks
            const int r  = c >> 4;            // key row 0..63
            const int c4 = (c & 15) * 4;      // d col
            const float4 kv = *(const float4*)(k + base + (long)(k0 + r) * DK_ + c4);
            ushort4 kb;
            kb.x = f2bf(kv.x); kb.y = f2bf(kv.y); kb.z = f2bf(kv.z); kb.w = f2bf(kv.w);
            *(ushort4*)&Kt[r][c4] = kb;
            const float4 vv = *(const float4*)(v + base + (long)(k0 + r) * DK_ + c4);
            Vt[c4 + 0][r] = f2bf(vv.x);
            Vt[c4 + 1][r] = f2bf(vv.y);
            Vt[c4 + 2][r] = f2bf(vv.z);
            Vt[c4 + 3][r] = f2bf(vv.w);
        }
        __syncthreads();

        // ---- QK^T: S[16q x 64k] per wave ----
        f32x4 sf[4];
        #pragma unroll
        for (int kt = 0; kt < 4; ++kt) {
            f32x4 acc = (f32x4){0.f, 0.f, 0.f, 0.f};
            short8 kf0 = *(const short8*)&Kt[kt * 16 + l15][lg * 8];
            acc = __builtin_amdgcn_mfma_f32_16x16x32_bf16(qf[0], kf0, acc, 0, 0, 0);
            short8 kf1 = *(const short8*)&Kt[kt * 16 + l15][32 + lg * 8];
            acc = __builtin_amdgcn_mfma_f32_16x16x32_bf16(qf[1], kf1, acc, 0, 0, 0);
            sf[kt] = acc;
        }

        // ---- scale + mask + online softmax ----
        float pm[4];
        #pragma unroll
        for (int r = 0; r < 4; ++r) pm[r] = -1e30f;
        #pragma unroll
        for (int kt = 0; kt < 4; ++kt) {
            const int j = k0 + kt * 16 + l15;
            #pragma unroll
            for (int r = 0; r < 4; ++r) {
                const int i = rowb + r;
                float s = sf[kt][r] * 0.125f;
                const bool valid = (j <= i) && (j < slen);
                s = valid ? s : -1e30f;
                sf[kt][r] = s;
                pm[r] = fmaxf(pm[r], s);
            }
        }
        #pragma unroll
        for (int r = 0; r < 4; ++r) {
            #pragma unroll
            for (int off = 1; off < 16; off <<= 1)
                pm[r] = fmaxf(pm[r], __shfl_xor(pm[r], off, 64));
        }
        float resc[4], rs[4];
        #pragma unroll
        for (int r = 0; r < 4; ++r) {
            const float mn = fmaxf(m_[r], pm[r]);
            resc[r] = exp2f((m_[r] - mn) * L2E);
            m_[r] = mn;
            rs[r] = 0.f;
        }
        #pragma unroll
        for (int kt = 0; kt < 4; ++kt) {
            #pragma unroll
            for (int r = 0; r < 4; ++r) {
                const float p = exp2f((sf[kt][r] - m_[r]) * L2E);
                sf[kt][r] = p;
                rs[r] += p;
            }
        }
        #pragma unroll
        for (int r = 0; r < 4; ++r) {
            #pragma unroll
            for (int off = 1; off < 16; off <<= 1)
                rs[r] += __shfl_xor(rs[r], off, 64);
            l_[r] = l_[r] * resc[r] + rs[r];
        }
        #pragma unroll
        for (int dt = 0; dt < 4; ++dt) {
            #pragma unroll
            for (int r = 0; r < 4; ++r) O[dt][r] *= resc[r];
        }

        // ---- P -> LDS (re-layout D-frag -> A-frag) ----
        #pragma unroll
        for (int kt = 0; kt < 4; ++kt) {
            #pragma unroll
            for (int r = 0; r < 4; ++r)
                Pl[wid][lg * 4 + r][kt * 16 + l15] = f2bf(sf[kt][r]);
        }
        // same-wave LDS RAW: compiler inserts lgkmcnt wait

        // ---- PV: O[16q x 64d] += P[16x64] * V[64x64] ----
        short8 pa0 = *(const short8*)&Pl[wid][l15][lg * 8];
        short8 pa1 = *(const short8*)&Pl[wid][l15][32 + lg * 8];
        #pragma unroll
        for (int dt = 0; dt < 4; ++dt) {
            short8 vb0 = *(const short8*)&Vt[dt * 16 + l15][lg * 8];
            short8 vb1 = *(const short8*)&Vt[dt * 16 + l15][32 + lg * 8];
            O[dt] = __builtin_amdgcn_mfma_f32_16x16x32_bf16(pa0, vb0, O[dt], 0, 0, 0);
            O[dt] = __builtin_amdgcn_mfma_f32_16x16x32_bf16(pa1, vb1, O[dt], 0, 0, 0);
        }
        __syncthreads();
    }

    // ---- epilogue: O / l ----
    #pragma unroll
    for (int r = 0; r < 4; ++r) {
        const float inv = 1.0f / l_[r];
        const int row = rowb + r;
        #pragma unroll
        for (int dt = 0; dt < 4; ++dt)
            out[base + (long)row * DK_ + dt * 16 + l15] = O[dt][r] * inv;
    }
}

extern "C" void kernel_launch(void* const* d_in, const int* in_sizes, int n_in,
                              void* d_out, int out_size, void* d_ws, size_t ws_size,
                              hipStream_t stream) {
    const float* q = (const float*)d_in[0];
    const float* k = (const float*)d_in[1];
    const float* v = (const float*)d_in[2];
    const int* sen_len = (const int*)d_in[3];
    float* out = (float*)d_out;

    dim3 grid(S_ / 64, B_ * H_);
    dim3 block(256);
    hipLaunchKernelGGL(attn_fwd, grid, block, 0, stream, q, k, v, sen_len, out);
}

// Round 3
// 323.702 us; speedup vs baseline: 1.2317x; 1.2317x over previous
//
#include <hip/hip_runtime.h>
#include <hip/hip_bf16.h>

#define B_   4
#define H_   16
#define S_   2048
#define DK_  64
#define NBH  64
// scale = 1/sqrt(64) * log2(e), folded into Q so P = exp2(S - m) directly
#define QSCALE (0.125f * 1.44269504f)

typedef __attribute__((ext_vector_type(8))) short short8;
typedef __attribute__((ext_vector_type(4))) float f32x4;

__device__ __forceinline__ unsigned short f2bf(float f) {
    union { float f; unsigned int u; } x; x.f = f;
    unsigned int r = x.u + 0x7fffu + ((x.u >> 16) & 1u);
    return (unsigned short)(r >> 16);
}

// ---- pre-pass 1: K f32 -> bf16 (same layout) ----
__global__ __launch_bounds__(256) void conv_k(const float* __restrict__ in,
                                              unsigned short* __restrict__ out) {
    const long i = (long)(blockIdx.x * 256 + threadIdx.x) * 8;
    const float4* p = (const float4*)(in + i);
    float4 a = p[0], b = p[1];
    short8 f;
    f[0] = (short)f2bf(a.x); f[1] = (short)f2bf(a.y);
    f[2] = (short)f2bf(a.z); f[3] = (short)f2bf(a.w);
    f[4] = (short)f2bf(b.x); f[5] = (short)f2bf(b.y);
    f[6] = (short)f2bf(b.z); f[7] = (short)f2bf(b.w);
    *(short8*)(out + i) = f;
}

// ---- pre-pass 2: V f32 [bh][s][d] -> bf16 V^T [bh][d][s] ----
__global__ __launch_bounds__(256) void transp_v(const float* __restrict__ v,
                                                unsigned short* __restrict__ vt) {
    const int s0 = blockIdx.x * 64;
    const int bh = blockIdx.y;
    const int s  = threadIdx.x & 63;
    const int dq = threadIdx.x >> 6;
    const float* src = v + ((long)bh * S_ + s0 + s) * DK_;
    unsigned short* dst = vt + (long)bh * DK_ * S_ + s0 + s;
    #pragma unroll
    for (int j4 = 0; j4 < 4; ++j4) {
        const int d4 = dq * 16 + j4 * 4;
        float4 a = *(const float4*)(src + d4);
        dst[(long)(d4 + 0) * S_] = f2bf(a.x);
        dst[(long)(d4 + 1) * S_] = f2bf(a.y);
        dst[(long)(d4 + 2) * S_] = f2bf(a.z);
        dst[(long)(d4 + 3) * S_] = f2bf(a.w);
    }
}

// ---- main attention: QBLK=128 (4 waves x 32 rows), KVBLK=64, XOR-swizzled LDS ----
template <bool PRECONV>
__global__ __launch_bounds__(256) void attn_fwd2(
    const float* __restrict__ q, const float* __restrict__ k32,
    const float* __restrict__ v32, const unsigned short* __restrict__ kbf,
    const unsigned short* __restrict__ vtbf, const int* __restrict__ sen_len,
    float* __restrict__ out)
{
    const int qt = blockIdx.x;
    const int bh = blockIdx.y;
    const int b  = bh >> 4;
    const int q0 = qt * 128;
    const long base = (long)bh * S_ * DK_;

    const int tid  = threadIdx.x;
    const int wid  = tid >> 6;
    const int lane = tid & 63;
    const int l15  = lane & 15;
    const int lg   = lane >> 4;

    // 128B rows, XOR-swizzled: byte ^= (row&7)<<4 within row
    __shared__ unsigned short Klds[64 * 64];      // [key][d]
    __shared__ unsigned short Vlds[64 * 64];      // [d][key]
    __shared__ unsigned short Plds[4][32 * 64];   // per-wave [qrow][key]
    char* const KldsB = (char*)Klds;
    char* const VldsB = (char*)Vlds;
    char* const PldsB = (char*)&Plds[wid][0];

    const int slen = sen_len[b];

    // ---- Q fragments (scaled by 1/8*log2e, held whole kernel) ----
    short8 qf[2][2];
    #pragma unroll
    for (int mt = 0; mt < 2; ++mt) {
        const int row = q0 + wid * 32 + mt * 16 + l15;
        const float* qp = q + base + (long)row * DK_ + lg * 8;
        #pragma unroll
        for (int ks = 0; ks < 2; ++ks) {
            float4 a = *(const float4*)(qp + ks * 32);
            float4 c = *(const float4*)(qp + ks * 32 + 4);
            short8 f;
            f[0] = (short)f2bf(a.x * QSCALE); f[1] = (short)f2bf(a.y * QSCALE);
            f[2] = (short)f2bf(a.z * QSCALE); f[3] = (short)f2bf(a.w * QSCALE);
            f[4] = (short)f2bf(c.x * QSCALE); f[5] = (short)f2bf(c.y * QSCALE);
            f[6] = (short)f2bf(c.z * QSCALE); f[7] = (short)f2bf(c.w * QSCALE);
            qf[mt][ks] = f;
        }
    }

    f32x4 O[2][4];
    float m_[2][4], l_[2][4];
    #pragma unroll
    for (int mt = 0; mt < 2; ++mt) {
        #pragma unroll
        for (int dt = 0; dt < 4; ++dt) O[mt][dt] = (f32x4){0.f, 0.f, 0.f, 0.f};
        #pragma unroll
        for (int r = 0; r < 4; ++r) { m_[mt][r] = -INFINITY; l_[mt][r] = 0.f; }
    }

    const int nk     = min(q0 + 128, slen);
    const int ntiles = (nk + 63) >> 6;
    const int wmax   = q0 + wid * 32 + 31;   // last q-row this wave owns

    for (int t = 0; t < ntiles; ++t) {
        const int k0 = t * 64;

        // ---- stage K [key][d] and V [d][key] into swizzled LDS ----
        if (PRECONV) {
            const unsigned short* ksrc = kbf + base + (long)k0 * DK_;
            const unsigned short* vsrc = vtbf + (long)bh * DK_ * S_ + k0;
            #pragma unroll
            for (int it = 0; it < 2; ++it) {
                const int c = tid + 256 * it;
                const int r = c >> 3, slot = c & 7;
                short8 kv = *(const short8*)(ksrc + r * DK_ + slot * 8);
                *(short8*)(KldsB + r * 128 + ((slot * 16) ^ ((r & 7) << 4))) = kv;
                short8 vv = *(const short8*)(vsrc + (long)r * S_ + slot * 8);
                *(short8*)(VldsB + r * 128 + ((slot * 16) ^ ((r & 7) << 4))) = vv;
            }
        } else {
            const float* ks32 = k32 + base + (long)k0 * DK_;
            #pragma unroll
            for (int it = 0; it < 2; ++it) {
                const int c = tid + 256 * it;
                const int r = c >> 3, slot = c & 7;
                const float4* p = (const float4*)(ks32 + r * DK_ + slot * 8);
                float4 a = p[0], bq = p[1];
                short8 f;
                f[0] = (short)f2bf(a.x);  f[1] = (short)f2bf(a.y);
                f[2] = (short)f2bf(a.z);  f[3] = (short)f2bf(a.w);
                f[4] = (short)f2bf(bq.x); f[5] = (short)f2bf(bq.y);
                f[6] = (short)f2bf(bq.z); f[7] = (short)f2bf(bq.w);
                *(short8*)(KldsB + r * 128 + ((slot * 16) ^ ((r & 7) << 4))) = f;
            }
            const float* vs32 = v32 + base + (long)k0 * DK_;
            #pragma unroll
            for (int it = 0; it < 4; ++it) {
                const int c = tid + 256 * it;
                const int s = c >> 4, d4 = (c & 15) * 4;
                float4 a = *(const float4*)(vs32 + s * DK_ + d4);
                unsigned short vals[4] = {f2bf(a.x), f2bf(a.y), f2bf(a.z), f2bf(a.w)};
                #pragma unroll
                for (int j = 0; j < 4; ++j)
                    *(unsigned short*)(VldsB + (d4 + j) * 128 +
                                       ((2 * s) ^ (((d4 + j) & 7) << 4))) = vals[j];
            }
        }
        __syncthreads();

        if (k0 <= wmax) {   // tile not fully causal-masked for this wave
            // ---- K fragments ----
            short8 kf[4][2];
            #pragma unroll
            for (int kt = 0; kt < 4; ++kt) {
                const int row = kt * 16 + l15;
                const int sw = (row & 7) << 4;
                kf[kt][0] = *(const short8*)(KldsB + row * 128 + ((lg * 16) ^ sw));
                kf[kt][1] = *(const short8*)(KldsB + row * 128 + ((64 + lg * 16) ^ sw));
            }
            // ---- QK^T ----
            f32x4 sf[2][4];
            #pragma unroll
            for (int mt = 0; mt < 2; ++mt)
                #pragma unroll
                for (int kt = 0; kt < 4; ++kt) {
                    f32x4 acc = (f32x4){0.f, 0.f, 0.f, 0.f};
                    acc = __builtin_amdgcn_mfma_f32_16x16x32_bf16(qf[mt][0], kf[kt][0], acc, 0, 0, 0);
                    acc = __builtin_amdgcn_mfma_f32_16x16x32_bf16(qf[mt][1], kf[kt][1], acc, 0, 0, 0);
                    sf[mt][kt] = acc;
                }

            // ---- mask (only when tile touches diagonal or padding) ----
            const bool need_mask = (k0 + 63 > q0) || (k0 + 63 >= slen);
            if (need_mask) {
                #pragma unroll
                for (int mt = 0; mt < 2; ++mt) {
                    const int ib = q0 + wid * 32 + mt * 16 + lg * 4;
                    #pragma unroll
                    for (int kt = 0; kt < 4; ++kt) {
                        const int j = k0 + kt * 16 + l15;
                        #pragma unroll
                        for (int r = 0; r < 4; ++r)
                            if (!((j <= ib + r) && (j < slen))) sf[mt][kt][r] = -1e30f;
                    }
                }
            }

            // ---- online softmax (P in log2 units already) ----
            #pragma unroll
            for (int mt = 0; mt < 2; ++mt) {
                float pm[4];
                #pragma unroll
                for (int r = 0; r < 4; ++r) {
                    pm[r] = fmaxf(fmaxf(sf[mt][0][r], sf[mt][1][r]),
                                  fmaxf(sf[mt][2][r], sf[mt][3][r]));
                    #pragma unroll
                    for (int off = 1; off < 16; off <<= 1)
                        pm[r] = fmaxf(pm[r], __shfl_xor(pm[r], off, 64));
                }
                float resc[4], rs[4];
                #pragma unroll
                for (int r = 0; r < 4; ++r) {
                    const float mn = fmaxf(m_[mt][r], pm[r]);
                    resc[r] = exp2f(m_[mt][r] - mn);
                    m_[mt][r] = mn;
                    rs[r] = 0.f;
                }
                #pragma unroll
                for (int kt = 0; kt < 4; ++kt)
                    #pragma unroll
                    for (int r = 0; r < 4; ++r) {
                        const float p = exp2f(sf[mt][kt][r] - m_[mt][r]);
                        sf[mt][kt][r] = p;
                        rs[r] += p;
                    }
                #pragma unroll
                for (int r = 0; r < 4; ++r) {
                    #pragma unroll
                    for (int off = 1; off < 16; off <<= 1)
                        rs[r] += __shfl_xor(rs[r], off, 64);
                    l_[mt][r] = l_[mt][r] * resc[r] + rs[r];
                }
                #pragma unroll
                for (int dt = 0; dt < 4; ++dt)
                    #pragma unroll
                    for (int r = 0; r < 4; ++r) O[mt][dt][r] *= resc[r];
            }

            // ---- P -> per-wave LDS (swizzled scalar writes) ----
            #pragma unroll
            for (int mt = 0; mt < 2; ++mt)
                #pragma unroll
                for (int kt = 0; kt < 4; ++kt)
                    #pragma unroll
                    for (int r = 0; r < 4; ++r) {
                        const int row = mt * 16 + lg * 4 + r;
                        const int col = kt * 16 + l15;
                        *(unsigned short*)(PldsB + row * 128 +
                                           ((col * 2) ^ ((row & 7) << 4))) = f2bf(sf[mt][kt][r]);
                    }

            // ---- P fragments (same-wave RAW; compiler inserts lgkmcnt) ----
            short8 pa[2][2];
            #pragma unroll
            for (int mt = 0; mt < 2; ++mt) {
                const int row = mt * 16 + l15;
                const int sw = (row & 7) << 4;
                pa[mt][0] = *(const short8*)(PldsB + row * 128 + ((lg * 16) ^ sw));
                pa[mt][1] = *(const short8*)(PldsB + row * 128 + ((64 + lg * 16) ^ sw));
            }

            // ---- PV ----
            #pragma unroll
            for (int dt = 0; dt < 4; ++dt) {
                const int row = dt * 16 + l15;
                const int sw = (row & 7) << 4;
                short8 vb0 = *(const short8*)(VldsB + row * 128 + ((lg * 16) ^ sw));
                short8 vb1 = *(const short8*)(VldsB + row * 128 + ((64 + lg * 16) ^ sw));
                O[0][dt] = __builtin_amdgcn_mfma_f32_16x16x32_bf16(pa[0][0], vb0, O[0][dt], 0, 0, 0);
                O[0][dt] = __builtin_amdgcn_mfma_f32_16x16x32_bf16(pa[0][1], vb1, O[0][dt], 0, 0, 0);
                O[1][dt] = __builtin_amdgcn_mfma_f32_16x16x32_bf16(pa[1][0], vb0, O[1][dt], 0, 0, 0);
                O[1][dt] = __builtin_amdgcn_mfma_f32_16x16x32_bf16(pa[1][1], vb1, O[1][dt], 0, 0, 0);
            }
        }
        __syncthreads();
    }

    // ---- epilogue ----
    #pragma unroll
    for (int mt = 0; mt < 2; ++mt)
        #pragma unroll
        for (int r = 0; r < 4; ++r) {
            const float inv = 1.0f / l_[mt][r];
            const int row = q0 + wid * 32 + mt * 16 + lg * 4 + r;
            float* op = out + base + (long)row * DK_ + l15;
            #pragma unroll
            for (int dt = 0; dt < 4; ++dt) op[dt * 16] = O[mt][dt][r] * inv;
        }
}

extern "C" void kernel_launch(void* const* d_in, const int* in_sizes, int n_in,
                              void* d_out, int out_size, void* d_ws, size_t ws_size,
                              hipStream_t stream) {
    const float* q = (const float*)d_in[0];
    const float* k = (const float*)d_in[1];
    const float* v = (const float*)d_in[2];
    const int* sen_len = (const int*)d_in[3];
    float* out = (float*)d_out;

    const size_t kv_elems = (size_t)NBH * S_ * DK_;   // 8.39M
    const bool pre = ws_size >= kv_elems * 2 * sizeof(unsigned short);
    unsigned short* kbf  = (unsigned short*)d_ws;
    unsigned short* vtbf = kbf + kv_elems;

    if (pre) {
        conv_k<<<dim3((unsigned)(kv_elems / 2048)), dim3(256), 0, stream>>>(k, kbf);
        transp_v<<<dim3(S_ / 64, NBH), dim3(256), 0, stream>>>(v, vtbf);
        attn_fwd2<true><<<dim3(S_ / 128, NBH), dim3(256), 0, stream>>>(
            q, k, v, kbf, vtbf, sen_len, out);
    } else {
        attn_fwd2<false><<<dim3(S_ / 128, NBH), dim3(256), 0, stream>>>(
            q, k, v, kbf, vtbf, sen_len, out);
    }
}

// Round 4
// 229.712 us; speedup vs baseline: 1.7357x; 1.4092x over previous
//
#include <hip/hip_runtime.h>
#include <hip/hip_bf16.h>

#define B_   4
#define H_   16
#define S_   2048
#define DK_  64
#define NBH  64
// scale = 1/sqrt(64) * log2(e), folded into Q so P = exp2(S - m) directly
#define QSCALE (0.125f * 1.44269504f)

typedef __attribute__((ext_vector_type(8)))  short    short8;
typedef __attribute__((ext_vector_type(4)))  float    f32x4;
typedef __attribute__((ext_vector_type(16))) float    f32x16;
typedef __attribute__((ext_vector_type(4)))  unsigned u32x4;

__device__ __forceinline__ unsigned short f2bf(float f) {
    union { float f; unsigned int u; } x; x.f = f;
    unsigned int r = x.u + 0x7fffu + ((x.u >> 16) & 1u);
    return (unsigned short)(r >> 16);
}

// pack 2 f32 -> 2 bf16 in one u32 (lo = a, hi = b)
__device__ __forceinline__ unsigned cvtpk(float a, float b) {
    unsigned r;
    asm("v_cvt_pk_bf16_f32 %0, %1, %2" : "=v"(r) : "v"(a), "v"(b));
    return r;
}
// v_permlane32_swap_b32 a, b : a[32:63] <-> b[0:31]
__device__ __forceinline__ void pl32swap(unsigned& a, unsigned& b) {
    asm("v_permlane32_swap_b32 %0, %1" : "+v"(a), "+v"(b));
}

// ---- pre-pass 1: K f32 -> bf16 (same layout) ----
__global__ __launch_bounds__(256) void conv_k(const float* __restrict__ in,
                                              unsigned short* __restrict__ out) {
    const long i = (long)(blockIdx.x * 256 + threadIdx.x) * 8;
    const float4* p = (const float4*)(in + i);
    float4 a = p[0], b = p[1];
    short8 f;
    f[0] = (short)f2bf(a.x); f[1] = (short)f2bf(a.y);
    f[2] = (short)f2bf(a.z); f[3] = (short)f2bf(a.w);
    f[4] = (short)f2bf(b.x); f[5] = (short)f2bf(b.y);
    f[6] = (short)f2bf(b.z); f[7] = (short)f2bf(b.w);
    *(short8*)(out + i) = f;
}

// ---- pre-pass 2: V f32 [bh][s][d] -> bf16 V^T [bh][d][s] ----
__global__ __launch_bounds__(256) void transp_v(const float* __restrict__ v,
                                                unsigned short* __restrict__ vt) {
    const int s0 = blockIdx.x * 64;
    const int bh = blockIdx.y;
    const int s  = threadIdx.x & 63;
    const int dq = threadIdx.x >> 6;
    const float* src = v + ((long)bh * S_ + s0 + s) * DK_;
    unsigned short* dst = vt + (long)bh * DK_ * S_ + s0 + s;
    #pragma unroll
    for (int j4 = 0; j4 < 4; ++j4) {
        const int d4 = dq * 16 + j4 * 4;
        float4 a = *(const float4*)(src + d4);
        dst[(long)(d4 + 0) * S_] = f2bf(a.x);
        dst[(long)(d4 + 1) * S_] = f2bf(a.y);
        dst[(long)(d4 + 2) * S_] = f2bf(a.z);
        dst[(long)(d4 + 3) * S_] = f2bf(a.w);
    }
}

// ---- main attention: swapped QK^T, 32x32x16 MFMA, in-register softmax ----
// 4 waves x 32 q-rows = QBLK 128; KVBLK = 64; LDS = K tile + V^T tile only.
template <bool PRECONV>
__global__ __launch_bounds__(256, 2) void attn_fwd3(
    const float* __restrict__ q, const float* __restrict__ k32,
    const float* __restrict__ v32, const unsigned short* __restrict__ kbf,
    const unsigned short* __restrict__ vtbf, const int* __restrict__ sen_len,
    float* __restrict__ out)
{
    const int qt = (S_ / 128 - 1) - blockIdx.x;   // heavy tiles dispatch first
    const int bh = blockIdx.y;
    const int b  = bh >> 4;
    const int q0 = qt * 128;
    const long base = (long)bh * S_ * DK_;

    const int tid  = threadIdx.x;
    const int wid  = tid >> 6;
    const int lane = tid & 63;
    const int l31  = lane & 31;
    const int hi   = lane >> 5;

    // 64 rows x 128B, swizzled: byte ^= (row&7)<<4
    __shared__ unsigned short Klds[64 * 64];   // [key][d]
    __shared__ unsigned short Vlds[64 * 64];   // [d][key]
    char* const KldsB = (char*)Klds;
    char* const VldsB = (char*)Vlds;

    const int slen = sen_len[b];
    const int q0w  = q0 + wid * 32;      // this wave's first q-row
    const int iq   = q0w + l31;          // this lane's q-row

    // ---- Q fragments: B-frag B[n=q][kd], kd = ks*16 + hi*8 + i ----
    short8 qf[4];
    {
        const float* qp = q + base + (long)iq * DK_ + hi * 8;
        #pragma unroll
        for (int ks = 0; ks < 4; ++ks) {
            float4 a = *(const float4*)(qp + ks * 16);
            float4 c = *(const float4*)(qp + ks * 16 + 4);
            short8 f;
            f[0] = (short)f2bf(a.x * QSCALE); f[1] = (short)f2bf(a.y * QSCALE);
            f[2] = (short)f2bf(a.z * QSCALE); f[3] = (short)f2bf(a.w * QSCALE);
            f[4] = (short)f2bf(c.x * QSCALE); f[5] = (short)f2bf(c.y * QSCALE);
            f[6] = (short)f2bf(c.z * QSCALE); f[7] = (short)f2bf(c.w * QSCALE);
            qf[ks] = f;
        }
    }

    f32x16 O0 = (f32x16)(0.f), O1 = (f32x16)(0.f);
    float m_ = -INFINITY, l_ = 0.f;

    const int nk     = min(q0 + 128, slen);
    const int ntiles = (nk + 63) >> 6;
    const int wmax   = q0w + 31;

    for (int t = 0; t < ntiles; ++t) {
        const int k0 = t * 64;

        // ---- stage K [key][d] and V^T [d][key] (swizzled) ----
        if (PRECONV) {
            const unsigned short* ksrc = kbf + base + (long)k0 * DK_;
            const unsigned short* vsrc = vtbf + (long)bh * DK_ * S_ + k0;
            #pragma unroll
            for (int it = 0; it < 2; ++it) {
                const int c = tid + 256 * it;
                const int r = c >> 3, slot = c & 7;
                const int dst = r * 128 + ((slot * 16) ^ ((r & 7) << 4));
                *(short8*)(KldsB + dst) = *(const short8*)(ksrc + r * DK_ + slot * 8);
                *(short8*)(VldsB + dst) = *(const short8*)(vsrc + (long)r * S_ + slot * 8);
            }
        } else {
            const float* ks32 = k32 + base + (long)k0 * DK_;
            #pragma unroll
            for (int it = 0; it < 2; ++it) {
                const int c = tid + 256 * it;
                const int r = c >> 3, slot = c & 7;
                const float4* p = (const float4*)(ks32 + r * DK_ + slot * 8);
                float4 a = p[0], bq = p[1];
                short8 f;
                f[0] = (short)f2bf(a.x);  f[1] = (short)f2bf(a.y);
                f[2] = (short)f2bf(a.z);  f[3] = (short)f2bf(a.w);
                f[4] = (short)f2bf(bq.x); f[5] = (short)f2bf(bq.y);
                f[6] = (short)f2bf(bq.z); f[7] = (short)f2bf(bq.w);
                *(short8*)(KldsB + r * 128 + ((slot * 16) ^ ((r & 7) << 4))) = f;
            }
            const float* vs32 = v32 + base + (long)k0 * DK_;
            #pragma unroll
            for (int it = 0; it < 4; ++it) {
                const int c = tid + 256 * it;
                const int s = c >> 4, d4 = (c & 15) * 4;
                float4 a = *(const float4*)(vs32 + s * DK_ + d4);
                unsigned short vals[4] = {f2bf(a.x), f2bf(a.y), f2bf(a.z), f2bf(a.w)};
                #pragma unroll
                for (int j = 0; j < 4; ++j)
                    *(unsigned short*)(VldsB + (d4 + j) * 128 +
                                       ((2 * s) ^ (((d4 + j) & 7) << 4))) = vals[j];
            }
        }
        __syncthreads();

        if (k0 <= wmax) {
            // ---- QK^T: S[64key x 32q], A = K rows, B = Q rows ----
            f32x16 s0 = (f32x16)(0.f), s1 = (f32x16)(0.f);
            #pragma unroll
            for (int ks = 0; ks < 4; ++ks) {
                const int col = ks * 32 + hi * 16;       // byte col, pre-swizzle
                const int r0 = l31, r1 = 32 + l31;
                short8 kf0 = *(const short8*)(KldsB + r0 * 128 + (col ^ ((r0 & 7) << 4)));
                short8 kf1 = *(const short8*)(KldsB + r1 * 128 + (col ^ ((r1 & 7) << 4)));
                s0 = __builtin_amdgcn_mfma_f32_32x32x16_bf16(kf0, qf[ks], s0, 0, 0, 0);
                s1 = __builtin_amdgcn_mfma_f32_32x32x16_bf16(kf1, qf[ks], s1, 0, 0, 0);
            }

            // ---- mask (skip for interior fully-valid tiles) ----
            if (!((k0 + 63 <= q0w) && (k0 + 63 < slen))) {
                #pragma unroll
                for (int r = 0; r < 16; ++r) {
                    const int joff = k0 + (r & 3) + 8 * (r >> 2) + 4 * hi;
                    const int j0 = joff, j1 = joff + 32;
                    if (!((j0 <= iq) && (j0 < slen))) s0[r] = -1e30f;
                    if (!((j1 <= iq) && (j1 < slen))) s1[r] = -1e30f;
                }
            }

            // ---- in-register online softmax (row = lane-local) ----
            float pm = s0[0];
            #pragma unroll
            for (int r = 1; r < 16; ++r) pm = fmaxf(pm, s0[r]);
            #pragma unroll
            for (int r = 0; r < 16; ++r) pm = fmaxf(pm, s1[r]);
            pm = fmaxf(pm, __shfl_xor(pm, 32, 64));
            const float mnew = fmaxf(m_, pm);
            const float resc = exp2f(m_ - mnew);
            m_ = mnew;
            float rs = 0.f;
            #pragma unroll
            for (int r = 0; r < 16; ++r) { s0[r] = exp2f(s0[r] - mnew); rs += s0[r]; }
            #pragma unroll
            for (int r = 0; r < 16; ++r) { s1[r] = exp2f(s1[r] - mnew); rs += s1[r]; }
            rs += __shfl_xor(rs, 32, 64);
            l_ = l_ * resc + rs;
            O0 *= resc;
            O1 *= resc;

            // ---- P -> bf16 B-frags in-register (cvt_pk + permlane32_swap) ----
            // slice s covers keys k0 + s*16 .. +15; frag words valid for both hi halves
            u32x4 pw[4];
            {
                unsigned a0 = cvtpk(s0[0], s0[1]),  c0 = cvtpk(s0[2], s0[3]);
                unsigned b0 = cvtpk(s0[4], s0[5]),  d0 = cvtpk(s0[6], s0[7]);
                pl32swap(a0, b0); pl32swap(c0, d0);
                pw[0] = (u32x4){a0, c0, b0, d0};
                unsigned a1 = cvtpk(s0[8], s0[9]),  c1 = cvtpk(s0[10], s0[11]);
                unsigned b1 = cvtpk(s0[12], s0[13]), d1 = cvtpk(s0[14], s0[15]);
                pl32swap(a1, b1); pl32swap(c1, d1);
                pw[1] = (u32x4){a1, c1, b1, d1};
                unsigned a2 = cvtpk(s1[0], s1[1]),  c2 = cvtpk(s1[2], s1[3]);
                unsigned b2 = cvtpk(s1[4], s1[5]),  d2 = cvtpk(s1[6], s1[7]);
                pl32swap(a2, b2); pl32swap(c2, d2);
                pw[2] = (u32x4){a2, c2, b2, d2};
                unsigned a3 = cvtpk(s1[8], s1[9]),  c3 = cvtpk(s1[10], s1[11]);
                unsigned b3 = cvtpk(s1[12], s1[13]), d3 = cvtpk(s1[14], s1[15]);
                pl32swap(a3, b3); pl32swap(c3, d3);
                pw[3] = (u32x4){a3, c3, b3, d3};
            }

            // ---- PV: O[64d x 32q] += V^T[d][k] * P[k][q] ----
            #pragma unroll
            for (int s = 0; s < 4; ++s) {
                short8 pf = __builtin_bit_cast(short8, pw[s]);
                const int col = s * 32 + hi * 16;
                const int r0 = l31, r1 = 32 + l31;
                short8 vf0 = *(const short8*)(VldsB + r0 * 128 + (col ^ ((r0 & 7) << 4)));
                short8 vf1 = *(const short8*)(VldsB + r1 * 128 + (col ^ ((r1 & 7) << 4)));
                O0 = __builtin_amdgcn_mfma_f32_32x32x16_bf16(vf0, pf, O0, 0, 0, 0);
                O1 = __builtin_amdgcn_mfma_f32_32x32x16_bf16(vf1, pf, O1, 0, 0, 0);
            }
        }
        __syncthreads();
    }

    // ---- epilogue: lane owns q-row iq; O reg r -> d = dblk*32 + (r&3)+8*(r>>2)+4*hi ----
    const float inv = 1.0f / l_;
    float* op = out + base + (long)iq * DK_;
    #pragma unroll
    for (int rq = 0; rq < 4; ++rq) {
        float4 f0, f1;
        f0.x = O0[rq * 4 + 0] * inv; f0.y = O0[rq * 4 + 1] * inv;
        f0.z = O0[rq * 4 + 2] * inv; f0.w = O0[rq * 4 + 3] * inv;
        f1.x = O1[rq * 4 + 0] * inv; f1.y = O1[rq * 4 + 1] * inv;
        f1.z = O1[rq * 4 + 2] * inv; f1.w = O1[rq * 4 + 3] * inv;
        *(float4*)(op + rq * 8 + hi * 4)      = f0;
        *(float4*)(op + 32 + rq * 8 + hi * 4) = f1;
    }
}

extern "C" void kernel_launch(void* const* d_in, const int* in_sizes, int n_in,
                              void* d_out, int out_size, void* d_ws, size_t ws_size,
                              hipStream_t stream) {
    const float* q = (const float*)d_in[0];
    const float* k = (const float*)d_in[1];
    const float* v = (const float*)d_in[2];
    const int* sen_len = (const int*)d_in[3];
    float* out = (float*)d_out;

    const size_t kv_elems = (size_t)NBH * S_ * DK_;   // 8.39M
    const bool pre = ws_size >= kv_elems * 2 * sizeof(unsigned short);
    unsigned short* kbf  = (unsigned short*)d_ws;
    unsigned short* vtbf = kbf + kv_elems;

    if (pre) {
        conv_k<<<dim3((unsigned)(kv_elems / 2048)), dim3(256), 0, stream>>>(k, kbf);
        transp_v<<<dim3(S_ / 64, NBH), dim3(256), 0, stream>>>(v, vtbf);
        attn_fwd3<true><<<dim3(S_ / 128, NBH), dim3(256), 0, stream>>>(
            q, k, v, kbf, vtbf, sen_len, out);
    } else {
        attn_fwd3<false><<<dim3(S_ / 128, NBH), dim3(256), 0, stream>>>(
            q, k, v, kbf, vtbf, sen_len, out);
    }
}